// Round 6
// baseline (33.735 us; speedup 1.0000x reference)
//
#include <hip/hip_runtime.h>
#include <hip/hip_bf16.h>

#define DD 256
#define SS 128
#define BB 16

typedef __attribute__((ext_vector_type(8))) short bf16x8;
typedef __attribute__((ext_vector_type(4))) float f32x4;

static __device__ __forceinline__ short f2bf(float f) {
    __hip_bfloat16 h = __float2bfloat16(f);
    return *reinterpret_cast<short*>(&h);
}
static __device__ __forceinline__ float bf2f(short s) {
    unsigned int u = ((unsigned int)(unsigned short)s) << 16;
    return __uint_as_float(u);
}

// ws layout (bytes):
//  Ebfg [2048][256] bf16   @ 0        (1 MB)   gathered embeddings
//  Wbfg [512][256]  bf16   @ 1 MB     (256 KB) [Wl;Wr]
//  Lsdh [B][S][D]   bf16   @ 1.25 MB  (1 MB)
//  Rsdh [B][S][D]   bf16   @ 2.25 MB  (1 MB)
//  sumLp[B][2][D]   f32    @ 3.25 MB  (32 KB)
//  sumRp[B][2][D]   f32    (32 KB)
//  absP [B][4][4][64] f32  (64 KB)

// ---------------- gather + convert to bf16 (one coalesced pass) ----------------
// grid 320: blocks 0..255 -> E (8 token rows each), 256..319 -> W (8 rows each)
__global__ __launch_bounds__(256) void k_conv(
    const int* __restrict__ X, const float* __restrict__ emb,
    const float* __restrict__ Wl, const float* __restrict__ Wr,
    short* __restrict__ Ebfg, short* __restrict__ Wbfg)
{
    __shared__ int toksh[8];
    const int tid = threadIdx.x;
    const int bx  = blockIdx.x;
    const int row = tid >> 5, g = tid & 31;   // 8 rows x 32 lanes x 8 floats

    if (bx < 256) {
        const int t0 = bx * 8;
        if (tid < 8) toksh[tid] = X[t0 + tid];   // X flat [B*S] == token index
        __syncthreads();
        const float* src = emb + (size_t)toksh[row] * DD + g * 8;
        float4 f0 = *(const float4*)(src);
        float4 f1 = *(const float4*)(src + 4);
        bf16x8 p;
        p[0]=f2bf(f0.x); p[1]=f2bf(f0.y); p[2]=f2bf(f0.z); p[3]=f2bf(f0.w);
        p[4]=f2bf(f1.x); p[5]=f2bf(f1.y); p[6]=f2bf(f1.z); p[7]=f2bf(f1.w);
        *(bf16x8*)(Ebfg + (size_t)(t0 + row) * DD + g * 8) = p;
    } else {
        const int w = (bx - 256) * 8 + row;       // 0..511, blocks never straddle 256
        const float* src = ((w < 256) ? (Wl + (size_t)w * DD)
                                      : (Wr + (size_t)(w - 256) * DD)) + g * 8;
        float4 f0 = *(const float4*)(src);
        float4 f1 = *(const float4*)(src + 4);
        bf16x8 p;
        p[0]=f2bf(f0.x); p[1]=f2bf(f0.y); p[2]=f2bf(f0.z); p[3]=f2bf(f0.w);
        p[4]=f2bf(f1.x); p[5]=f2bf(f1.y); p[6]=f2bf(f1.z); p[7]=f2bf(f1.w);
        *(bf16x8*)(Wbfg + (size_t)w * DD + g * 8) = p;
    }
}

// ---------------- projection: MFMA with fragments straight from L2 ----------------
// grid 512 = 32 tc(64 tok) x 16 cc(32 cols of L|R); 256 thr = 4 waves; no staging LDS.
__global__ __launch_bounds__(256) void k_proj(
    const short* __restrict__ Ebfg, const short* __restrict__ Wbfg,
    const float* __restrict__ bl, const float* __restrict__ br,
    short* __restrict__ Lsdh, short* __restrict__ Rsdh,
    float* __restrict__ sumLp, float* __restrict__ sumRp)
{
    __shared__ float redw[4 * 16];
    const int tid = threadIdx.x;
    const int bx  = blockIdx.x;
    const int tc  = bx >> 4;          // 0..31
    const int cc  = bx & 15;          // 0..15 (0-7 -> L, 8-15 -> R)
    const int b   = tc >> 1;
    const int s0  = (tc & 1) * 64;
    const int t0  = tc * 64;
    const int mat = cc >> 3;
    const int dr0 = (cc & 7) * 32;

    const int w    = tid >> 6;
    const int lane = tid & 63;
    const int wm = w >> 1, wn = w & 1;      // 32-token half x 16-col half
    const int lr = lane & 15, lk = lane >> 4;

    // fragment base pointers: lane (lr,lk) -> row, k-block. 16 rows x 64B = full lines.
    const short* Arow0 = Ebfg + (size_t)(t0 + wm * 32 + lr) * DD + lk * 8;
    const short* Arow1 = Arow0 + 16 * DD;
    const short* Brow  = Wbfg + (size_t)(mat * 256 + dr0 + wn * 16 + lr) * DD + lk * 8;

    f32x4 acc0 = {0.f,0.f,0.f,0.f}, acc1 = acc0;
#pragma unroll
    for (int ks = 0; ks < 8; ++ks) {
        bf16x8 a0 = *(const bf16x8*)(Arow0 + ks * 32);
        bf16x8 a1 = *(const bf16x8*)(Arow1 + ks * 32);
        bf16x8 b0 = *(const bf16x8*)(Brow  + ks * 32);
        acc0 = __builtin_amdgcn_mfma_f32_16x16x32_bf16(a0, b0, acc0, 0, 0, 0);
        acc1 = __builtin_amdgcn_mfma_f32_16x16x32_bf16(a1, b0, acc1, 0, 0, 0);
    }

    // bias + bf16 store to [b][s][d]. D mapping (m89-verified): col=lane&15, row=(lane>>4)*4+reg
    const float bv = ((mat == 0) ? bl : br)[dr0 + wn * 16 + lr];
    short* Tb = (mat == 0) ? Lsdh : Rsdh;
    const int dcol = dr0 + wn * 16 + lr;
#pragma unroll
    for (int reg = 0; reg < 4; ++reg) {
        int st = s0 + wm * 32 + lk * 4 + reg;
        Tb[((size_t)(b * SS) + st)      * DD + dcol] = f2bf(acc0[reg] + bv);
        Tb[((size_t)(b * SS) + st + 16) * DD + dcol] = f2bf(acc1[reg] + bv);
    }

    // token sums (separable mean term): 8 tokens/lane, reduce over lk via shfl
    float t8 = (acc0[0] + acc0[1] + acc0[2] + acc0[3]) + bv * 8.0f
             + (acc1[0] + acc1[1] + acc1[2] + acc1[3]);
    t8 += __shfl_xor(t8, 16);
    t8 += __shfl_xor(t8, 32);
    if (lane < 16) redw[w * 16 + lr] = t8;
    __syncthreads();
    if (tid < 32) {
        int wn2 = tid >> 4, c = tid & 15;
        float s = redw[(0 * 2 + wn2) * 16 + c] + redw[(1 * 2 + wn2) * 16 + c];
        float* sp = (mat == 0) ? sumLp : sumRp;
        sp[(b * 2 + (tc & 1)) * DD + dr0 + wn2 * 16 + c] = s;
    }
}

// ---------------- all-pairs |L_i + R_j| partial sums ----------------
// grid 256 = b x 4 dchunk(64) x 4 isplit(32); 256 threads = 64 d x 4 j-groups
__global__ __launch_bounds__(256) void k_pairs(
    const short* __restrict__ Lsdh, const short* __restrict__ Rsdh,
    float* __restrict__ absP)
{
    __shared__ float Ll[64 * 33];     // [d][i32]
    __shared__ float Rl[64 * 129];    // [d][j128]
    __shared__ float red[256];
    const int tid = threadIdx.x;
    const int bx  = blockIdx.x;
    const int b   = bx >> 4;
    const int dc  = (bx >> 2) & 3;
    const int is  = bx & 3;

    // L: 32 s-rows x 64 d bf16 (coalesced 16B/lane), transpose to Ll
    {
        int srow = tid >> 3, c8 = tid & 7;
        bf16x8 x = *(const bf16x8*)&Lsdh[((size_t)(b * SS) + is * 32 + srow) * DD + dc * 64 + c8 * 8];
#pragma unroll
        for (int q = 0; q < 8; ++q) Ll[(c8 * 8 + q) * 33 + srow] = bf2f(x[q]);
    }
    // R: 128 s-rows x 64 d bf16, transpose to Rl
#pragma unroll
    for (int it = 0; it < 4; ++it) {
        int v = it * 256 + tid;
        int j = v >> 3, c8 = v & 7;
        bf16x8 x = *(const bf16x8*)&Rsdh[((size_t)(b * SS) + j) * DD + dc * 64 + c8 * 8];
#pragma unroll
        for (int q = 0; q < 8; ++q) Rl[(c8 * 8 + q) * 129 + j] = bf2f(x[q]);
    }
    __syncthreads();

    const int dl = tid & 63;
    const int jg = tid >> 6;
    float rr[32];
#pragma unroll
    for (int j = 0; j < 32; ++j) rr[j] = Rl[dl * 129 + jg * 32 + j];

    float a0 = 0.f, a1 = 0.f, a2 = 0.f, a3 = 0.f;
#pragma unroll
    for (int i = 0; i < 32; ++i) {
        float l = Ll[dl * 33 + i];
#pragma unroll
        for (int j = 0; j < 32; j += 4) {
            a0 += fabsf(l + rr[j + 0]);
            a1 += fabsf(l + rr[j + 1]);
            a2 += fabsf(l + rr[j + 2]);
            a3 += fabsf(l + rr[j + 3]);
        }
    }
    red[tid] = (a0 + a1) + (a2 + a3);
    __syncthreads();
    if (tid < 64) {
        float s = red[tid] + red[tid + 64] + red[tid + 128] + red[tid + 192];
        absP[((b * 4 + dc) * 4 + is) * 64 + tid] = s;
    }
}

// ---------------- final: pooled affine ----------------
__global__ __launch_bounds__(256) void k_final(
    const float* __restrict__ sumLp, const float* __restrict__ sumRp,
    const float* __restrict__ absP,
    const float* __restrict__ Wrel, const float* __restrict__ brel,
    float* __restrict__ out)
{
    __shared__ float plds[DD];
    const int tid = threadIdx.x;
    const int b   = blockIdx.x;

    float sl = sumLp[(b * 2 + 0) * DD + tid] + sumLp[(b * 2 + 1) * DD + tid];
    float sr = sumRp[(b * 2 + 0) * DD + tid] + sumRp[(b * 2 + 1) * DD + tid];

    const int dc = tid >> 6, dl = tid & 63;
    float sa = 0.f;
#pragma unroll
    for (int is = 0; is < 4; ++is)
        sa += absP[((b * 4 + dc) * 4 + is) * 64 + dl];

    // pooled = (S*(sumL+sumR) + sumAbs) / (2*S*S)
    plds[tid] = (128.0f * (sl + sr) + sa) * (1.0f / 32768.0f);
    __syncthreads();

    float acc = brel[tid];
    const float4* w4 = (const float4*)(Wrel + (size_t)tid * DD);
#pragma unroll
    for (int k4 = 0; k4 < DD / 4; ++k4) {
        float4 p = *(float4*)&plds[k4 * 4];
        float4 w = w4[k4];
        acc = fmaf(p.x, w.x, acc);
        acc = fmaf(p.y, w.y, acc);
        acc = fmaf(p.z, w.z, acc);
        acc = fmaf(p.w, w.w, acc);
    }
    out[b * DD + tid] = acc;
}

extern "C" void kernel_launch(void* const* d_in, const int* in_sizes, int n_in,
                              void* d_out, int out_size, void* d_ws, size_t ws_size,
                              hipStream_t stream) {
    const int*   X    = (const int*)d_in[0];
    const float* emb  = (const float*)d_in[1];
    const float* Wl   = (const float*)d_in[2];
    const float* bl   = (const float*)d_in[3];
    const float* Wr   = (const float*)d_in[4];
    const float* br   = (const float*)d_in[5];
    const float* Wrel = (const float*)d_in[6];
    const float* brel = (const float*)d_in[7];
    float* out = (float*)d_out;

    char* base = (char*)d_ws;
    short* Ebfg  = (short*)(base);                       // 1 MB
    short* Wbfg  = (short*)(base + (1u << 20));          // 256 KB
    short* Lsdh  = (short*)(base + 1310720);             // 1 MB
    short* Rsdh  = (short*)(base + 2359296);             // 1 MB
    float* sumLp = (float*)(base + 3407872);             // 32 KB
    float* sumRp = (float*)(base + 3440640);             // 32 KB
    float* absP  = (float*)(base + 3473408);             // 64 KB

    k_conv<<<320, 256, 0, stream>>>(X, emb, Wl, Wr, Ebfg, Wbfg);
    k_proj<<<512, 256, 0, stream>>>(Ebfg, Wbfg, bl, br, Lsdh, Rsdh, sumLp, sumRp);
    k_pairs<<<256, 256, 0, stream>>>(Lsdh, Rsdh, absP);
    k_final<<<BB, 256, 0, stream>>>(sumLp, sumRp, absP, Wrel, brel, out);
}

// Round 7
// 31.787 us; speedup vs baseline: 1.0613x; 1.0613x over previous
//
#include <hip/hip_runtime.h>
#include <hip/hip_bf16.h>

#define DD 256
#define SS 128
#define BB 16

typedef __attribute__((ext_vector_type(8))) short bf16x8;
typedef __attribute__((ext_vector_type(4))) short bf16x4;
typedef __attribute__((ext_vector_type(4))) float f32x4;

static __device__ __forceinline__ short f2bf(float f) {
    __hip_bfloat16 h = __float2bfloat16(f);
    return *reinterpret_cast<short*>(&h);
}

// swizzled byte offset within a [64 rows][256 bf16 = 512B] LDS tile
static __device__ __forceinline__ int swz(int r, int kb) {
    return r * 512 + (kb ^ ((r & 7) << 4));
}

// ws layout (floats): sumLg [B][D], sumRg [B][D], absS [B][D]

// ---------------- fused: embed-gather + L/R projection (MFMA) + all-pairs ----------------
// grid 256 = B(16) x 16 d-chunks(16); 256 threads = 4 waves; 1 block/CU.
__global__ __launch_bounds__(256) void k_fused(
    const int* __restrict__ X, const float* __restrict__ emb,
    const float* __restrict__ Wl, const float* __restrict__ bl,
    const float* __restrict__ Wr, const float* __restrict__ br,
    float* __restrict__ sumLg, float* __restrict__ sumRg,
    float* __restrict__ absS)
{
    __shared__ __align__(16) short Ebf[64 * 256];     // 32 KB, swizzled bf16
    __shared__ __align__(16) float Lcol[16 * 132];    // [d][s], 16B-aligned rows
    __shared__ __align__(16) float Rcol[16 * 132];
    __shared__ float redA[256];
    __shared__ float redR[256];
    __shared__ float redL[16];
    __shared__ int toksh[SS];

    const int tid  = threadIdx.x;
    const int b    = blockIdx.x >> 4;
    const int dc   = blockIdx.x & 15;
    const int dr0  = dc * 16;
    const int w    = tid >> 6;
    const int lane = tid & 63;
    const int lr   = lane & 15, lk = lane >> 4;

    // ---- W fragments: f32 -> bf16 once, held in registers (64 VGPR) ----
    bf16x8 wlf[8], wrf[8];
    {
        const float* plw = Wl + (size_t)(dr0 + lr) * DD + lk * 8;
        const float* prw = Wr + (size_t)(dr0 + lr) * DD + lk * 8;
#pragma unroll
        for (int ks = 0; ks < 8; ++ks) {
            float4 f0 = *(const float4*)(plw + ks * 32);
            float4 f1 = *(const float4*)(plw + ks * 32 + 4);
            bf16x8 p;
            p[0]=f2bf(f0.x); p[1]=f2bf(f0.y); p[2]=f2bf(f0.z); p[3]=f2bf(f0.w);
            p[4]=f2bf(f1.x); p[5]=f2bf(f1.y); p[6]=f2bf(f1.z); p[7]=f2bf(f1.w);
            wlf[ks] = p;
            f0 = *(const float4*)(prw + ks * 32);
            f1 = *(const float4*)(prw + ks * 32 + 4);
            p[0]=f2bf(f0.x); p[1]=f2bf(f0.y); p[2]=f2bf(f0.z); p[3]=f2bf(f0.w);
            p[4]=f2bf(f1.x); p[5]=f2bf(f1.y); p[6]=f2bf(f1.z); p[7]=f2bf(f1.w);
            wrf[ks] = p;
        }
    }

    if (tid < SS) toksh[tid] = X[b * SS + tid];
    const float blv = bl[dr0 + lr];
    const float brv = br[dr0 + lr];
    __syncthreads();

    char* Eb = (char*)Ebf;

#pragma unroll
    for (int h = 0; h < 2; ++h) {
        // stage 64 tokens: coalesced 1KB-row gather, f32 -> bf16, swizzled
#pragma unroll
        for (int i = 0; i < 16; ++i) {
            int v = i * 256 + tid;
            int row = v >> 6, c4 = v & 63;
            float4 f = *(const float4*)&emb[(size_t)toksh[h * 64 + row] * DD + c4 * 4];
            bf16x4 p; p[0]=f2bf(f.x); p[1]=f2bf(f.y); p[2]=f2bf(f.z); p[3]=f2bf(f.w);
            *(bf16x4*)(Eb + swz(row, c4 * 8)) = p;
        }
        __syncthreads();

        f32x4 accL = {0.f,0.f,0.f,0.f}, accR = accL;
#pragma unroll
        for (int ks = 0; ks < 8; ++ks) {
            bf16x8 a = *(bf16x8*)(Eb + swz(w * 16 + lr, ks * 64 + lk * 16));
            accL = __builtin_amdgcn_mfma_f32_16x16x32_bf16(a, wlf[ks], accL, 0, 0, 0);
            accR = __builtin_amdgcn_mfma_f32_16x16x32_bf16(a, wrf[ks], accR, 0, 0, 0);
        }
        // C mapping (m89-verified): col = lane&15 (d), row = (lane>>4)*4 + reg (token)
#pragma unroll
        for (int reg = 0; reg < 4; ++reg) {
            int s = h * 64 + w * 16 + lk * 4 + reg;
            Lcol[lr * 132 + s] = accL[reg] + blv;
            Rcol[lr * 132 + s] = accR[reg] + brv;
        }
        __syncthreads();   // MFMA reads done before restage; Lcol/Rcol ready for pairs
    }

    // ---- all-pairs phase: thread (d, jg) handles 8 j's x 128 i's ----
    const int d = tid & 15, jg = tid >> 4;
    float rr[8];
    *(float4*)&rr[0] = *(float4*)&Rcol[d * 132 + jg * 8];
    *(float4*)&rr[4] = *(float4*)&Rcol[d * 132 + jg * 8 + 4];
    float srp = ((rr[0]+rr[1])+(rr[2]+rr[3])) + ((rr[4]+rr[5])+(rr[6]+rr[7]));

    float sl = 0.f;
    float a0 = 0.f, a1 = 0.f, a2 = 0.f, a3 = 0.f;
    for (int i = 0; i < 128; i += 4) {
        float4 l4 = *(float4*)&Lcol[d * 132 + i];
        sl += (l4.x + l4.y) + (l4.z + l4.w);
#pragma unroll
        for (int q = 0; q < 8; ++q) {
            a0 += fabsf(l4.x + rr[q]);
            a1 += fabsf(l4.y + rr[q]);
            a2 += fabsf(l4.z + rr[q]);
            a3 += fabsf(l4.w + rr[q]);
        }
    }
    redA[tid] = (a0 + a1) + (a2 + a3);
    redR[tid] = srp;
    if (jg == 0) redL[d] = sl;
    __syncthreads();

    if (tid < 16) {
        float sa = 0.f, sr = 0.f;
#pragma unroll
        for (int g = 0; g < 16; ++g) {
            sa += redA[g * 16 + tid];
            sr += redR[g * 16 + tid];
        }
        absS [b * DD + dr0 + tid] = sa;
        sumLg[b * DD + dr0 + tid] = redL[tid];
        sumRg[b * DD + dr0 + tid] = sr;
    }
}

// ---------------- final: pooled affine ----------------
__global__ __launch_bounds__(256) void k_final(
    const float* __restrict__ sumLg, const float* __restrict__ sumRg,
    const float* __restrict__ absS,
    const float* __restrict__ Wrel, const float* __restrict__ brel,
    float* __restrict__ out)
{
    __shared__ float plds[DD];
    const int tid = threadIdx.x;
    const int b   = blockIdx.x;

    float sl = sumLg[b * DD + tid];
    float sr = sumRg[b * DD + tid];
    float sa = absS [b * DD + tid];

    // pooled = (S*(sumL+sumR) + sumAbs) / (2*S*S)
    plds[tid] = (128.0f * (sl + sr) + sa) * (1.0f / 32768.0f);
    __syncthreads();

    float acc = brel[tid];
    const float4* w4 = (const float4*)(Wrel + (size_t)tid * DD);
#pragma unroll
    for (int k4 = 0; k4 < DD / 4; ++k4) {
        float4 p = *(float4*)&plds[k4 * 4];
        float4 w = w4[k4];
        acc = fmaf(p.x, w.x, acc);
        acc = fmaf(p.y, w.y, acc);
        acc = fmaf(p.z, w.z, acc);
        acc = fmaf(p.w, w.w, acc);
    }
    out[b * DD + tid] = acc;
}

extern "C" void kernel_launch(void* const* d_in, const int* in_sizes, int n_in,
                              void* d_out, int out_size, void* d_ws, size_t ws_size,
                              hipStream_t stream) {
    const int*   X    = (const int*)d_in[0];
    const float* emb  = (const float*)d_in[1];
    const float* Wl   = (const float*)d_in[2];
    const float* bl   = (const float*)d_in[3];
    const float* Wr   = (const float*)d_in[4];
    const float* br   = (const float*)d_in[5];
    const float* Wrel = (const float*)d_in[6];
    const float* brel = (const float*)d_in[7];
    float* out = (float*)d_out;

    float* ws    = (float*)d_ws;
    float* sumLg = ws;                 // [B][D]
    float* sumRg = sumLg + BB * DD;    // [B][D]
    float* absS  = sumRg + BB * DD;    // [B][D]

    k_fused<<<BB * 16, 256, 0, stream>>>(X, emb, Wl, bl, Wr, br,
                                         sumLg, sumRg, absS);
    k_final<<<BB, 256, 0, stream>>>(sumLg, sumRg, absS, Wrel, brel, out);
}

// Round 8
// 28.283 us; speedup vs baseline: 1.1928x; 1.1239x over previous
//
#include <hip/hip_runtime.h>
#include <hip/hip_bf16.h>

#define DD 256
#define SS 128
#define BB 16

typedef __attribute__((ext_vector_type(8))) short bf16x8;
typedef __attribute__((ext_vector_type(4))) short bf16x4;
typedef __attribute__((ext_vector_type(4))) float f32x4;

static __device__ __forceinline__ short f2bf(float f) {
    __hip_bfloat16 h = __float2bfloat16(f);
    return *reinterpret_cast<short*>(&h);
}

// swizzled byte offset within a [rows][256 bf16 = 512B] LDS tile
static __device__ __forceinline__ int swz(int r, int kb) {
    return r * 512 + (kb ^ ((r & 7) << 4));
}

// ws layout (floats): sumLg [B][D], sumRg [B][D], absS [B][D]

// ---------------- fused: gather + projection (MFMA) + all-pairs ----------------
// grid 256 = B(16) x 16 d-chunks(16); 512 threads = 8 waves -> 2 waves/SIMD.
__global__ __launch_bounds__(512, 2) void k_fused(
    const int* __restrict__ X, const float* __restrict__ emb,
    const float* __restrict__ Wl, const float* __restrict__ bl,
    const float* __restrict__ Wr, const float* __restrict__ br,
    float* __restrict__ sumLg, float* __restrict__ sumRg,
    float* __restrict__ absS)
{
    __shared__ __align__(16) short Ebf[128 * 256];    // 64 KB, swizzled bf16
    __shared__ __align__(16) float Lcol[16 * 132];    // [d][s]
    __shared__ __align__(16) float Rcol[16 * 132];
    __shared__ float redA[512];
    __shared__ float redwL[8 * 16];
    __shared__ float redwR[8 * 16];
    __shared__ int toksh[SS];

    const int tid  = threadIdx.x;
    // XCD-bijective swizzle: 32 consecutive logical blocks (2 batches) per XCD
    const int bx   = (blockIdx.x & 7) * 32 + (blockIdx.x >> 3);
    const int b    = bx >> 4;
    const int dc   = bx & 15;
    const int dr0  = dc * 16;
    const int w    = tid >> 6;          // wave 0..7 -> 16-token rows
    const int lane = tid & 63;
    const int lr   = lane & 15, lk = lane >> 4;
    const int c4   = tid & 63;          // column float4 within a 1KB row

    if (tid < SS) toksh[tid] = X[b * SS + tid];
    __syncthreads();

    char* Eb = (char*)Ebf;

    // ---- gather batch A (rows w, 8+w, ..., 56+w), issue all 8 loads ----
    float4 ga[8];
#pragma unroll
    for (int i = 0; i < 8; ++i)
        ga[i] = *(const float4*)&emb[(size_t)toksh[i * 8 + w] * DD + c4 * 4];

    // ---- W fragments: f32 -> bf16, in registers (cvt VALU hides under gather) ----
    bf16x8 wlf[8], wrf[8];
    {
        const float* plw = Wl + (size_t)(dr0 + lr) * DD + lk * 8;
        const float* prw = Wr + (size_t)(dr0 + lr) * DD + lk * 8;
#pragma unroll
        for (int ks = 0; ks < 8; ++ks) {
            float4 f0 = *(const float4*)(plw + ks * 32);
            float4 f1 = *(const float4*)(plw + ks * 32 + 4);
            bf16x8 p;
            p[0]=f2bf(f0.x); p[1]=f2bf(f0.y); p[2]=f2bf(f0.z); p[3]=f2bf(f0.w);
            p[4]=f2bf(f1.x); p[5]=f2bf(f1.y); p[6]=f2bf(f1.z); p[7]=f2bf(f1.w);
            wlf[ks] = p;
            f0 = *(const float4*)(prw + ks * 32);
            f1 = *(const float4*)(prw + ks * 32 + 4);
            p[0]=f2bf(f0.x); p[1]=f2bf(f0.y); p[2]=f2bf(f0.z); p[3]=f2bf(f0.w);
            p[4]=f2bf(f1.x); p[5]=f2bf(f1.y); p[6]=f2bf(f1.z); p[7]=f2bf(f1.w);
            wrf[ks] = p;
        }
    }

    // write batch A, then batch B
#pragma unroll
    for (int i = 0; i < 8; ++i) {
        bf16x4 p; p[0]=f2bf(ga[i].x); p[1]=f2bf(ga[i].y); p[2]=f2bf(ga[i].z); p[3]=f2bf(ga[i].w);
        *(bf16x4*)(Eb + swz(i * 8 + w, c4 * 8)) = p;
    }
#pragma unroll
    for (int i = 0; i < 8; ++i)
        ga[i] = *(const float4*)&emb[(size_t)toksh[64 + i * 8 + w] * DD + c4 * 4];
#pragma unroll
    for (int i = 0; i < 8; ++i) {
        bf16x4 p; p[0]=f2bf(ga[i].x); p[1]=f2bf(ga[i].y); p[2]=f2bf(ga[i].z); p[3]=f2bf(ga[i].w);
        *(bf16x4*)(Eb + swz(64 + i * 8 + w, c4 * 8)) = p;
    }
    __syncthreads();

    // ---- MFMA: wave w -> tokens w*16..w*16+15, 16 d's ----
    f32x4 accL = {0.f,0.f,0.f,0.f}, accR = accL;
#pragma unroll
    for (int ks = 0; ks < 8; ++ks) {
        bf16x8 a = *(bf16x8*)(Eb + swz(w * 16 + lr, ks * 64 + lk * 16));
        accL = __builtin_amdgcn_mfma_f32_16x16x32_bf16(a, wlf[ks], accL, 0, 0, 0);
        accR = __builtin_amdgcn_mfma_f32_16x16x32_bf16(a, wrf[ks], accR, 0, 0, 0);
    }
    const float blv = bl[dr0 + lr];
    const float brv = br[dr0 + lr];
    // C mapping (m89-verified): col = lane&15 (d), row = (lane>>4)*4 + reg (token)
#pragma unroll
    for (int reg = 0; reg < 4; ++reg) {
        int s = w * 16 + lk * 4 + reg;
        Lcol[lr * 132 + s] = accL[reg] + blv;
        Rcol[lr * 132 + s] = accR[reg] + brv;
    }
    // token sums: 4 tokens/lane (+bias), reduce over lk via shfl
    float tl = (accL[0] + accL[1]) + (accL[2] + accL[3]) + blv * 4.0f;
    float tr = (accR[0] + accR[1]) + (accR[2] + accR[3]) + brv * 4.0f;
    tl += __shfl_xor(tl, 16);  tr += __shfl_xor(tr, 16);
    tl += __shfl_xor(tl, 32);  tr += __shfl_xor(tr, 32);
    if (lane < 16) { redwL[w * 16 + lr] = tl; redwR[w * 16 + lr] = tr; }
    __syncthreads();

    // ---- all-pairs |L_i + R_j|: thread (d, jg) does 4 j's x 128 i's ----
    const int d = tid & 15, jg = tid >> 4;     // jg 0..31
    float rr[4];
    *(float4*)rr = *(float4*)&Rcol[d * 132 + jg * 4];

    float a0 = 0.f, a1 = 0.f, a2 = 0.f, a3 = 0.f;
    for (int i = 0; i < 128; i += 4) {
        float4 l4 = *(float4*)&Lcol[d * 132 + i];
#pragma unroll
        for (int q = 0; q < 4; ++q) {
            a0 += fabsf(l4.x + rr[q]);
            a1 += fabsf(l4.y + rr[q]);
            a2 += fabsf(l4.z + rr[q]);
            a3 += fabsf(l4.w + rr[q]);
        }
    }
    redA[tid] = (a0 + a1) + (a2 + a3);
    __syncthreads();

    if (tid < 16) {
        float sa = 0.f;
#pragma unroll
        for (int g = 0; g < 32; ++g) sa += redA[g * 16 + tid];
        float sl = 0.f, sr = 0.f;
#pragma unroll
        for (int wv = 0; wv < 8; ++wv) {
            sl += redwL[wv * 16 + tid];
            sr += redwR[wv * 16 + tid];
        }
        absS [b * DD + dr0 + tid] = sa;
        sumLg[b * DD + dr0 + tid] = sl;
        sumRg[b * DD + dr0 + tid] = sr;
    }
}

// ---------------- final: pooled affine ----------------
__global__ __launch_bounds__(256) void k_final(
    const float* __restrict__ sumLg, const float* __restrict__ sumRg,
    const float* __restrict__ absS,
    const float* __restrict__ Wrel, const float* __restrict__ brel,
    float* __restrict__ out)
{
    __shared__ float plds[DD];
    const int tid = threadIdx.x;
    const int b   = blockIdx.x;

    float sl = sumLg[b * DD + tid];
    float sr = sumRg[b * DD + tid];
    float sa = absS [b * DD + tid];

    // pooled = (S*(sumL+sumR) + sumAbs) / (2*S*S)
    plds[tid] = (128.0f * (sl + sr) + sa) * (1.0f / 32768.0f);
    __syncthreads();

    float acc = brel[tid];
    const float4* w4 = (const float4*)(Wrel + (size_t)tid * DD);
#pragma unroll
    for (int k4 = 0; k4 < DD / 4; ++k4) {
        float4 p = *(float4*)&plds[k4 * 4];
        float4 w = w4[k4];
        acc = fmaf(p.x, w.x, acc);
        acc = fmaf(p.y, w.y, acc);
        acc = fmaf(p.z, w.z, acc);
        acc = fmaf(p.w, w.w, acc);
    }
    out[b * DD + tid] = acc;
}

extern "C" void kernel_launch(void* const* d_in, const int* in_sizes, int n_in,
                              void* d_out, int out_size, void* d_ws, size_t ws_size,
                              hipStream_t stream) {
    const int*   X    = (const int*)d_in[0];
    const float* emb  = (const float*)d_in[1];
    const float* Wl   = (const float*)d_in[2];
    const float* bl   = (const float*)d_in[3];
    const float* Wr   = (const float*)d_in[4];
    const float* br   = (const float*)d_in[5];
    const float* Wrel = (const float*)d_in[6];
    const float* brel = (const float*)d_in[7];
    float* out = (float*)d_out;

    float* ws    = (float*)d_ws;
    float* sumLg = ws;                 // [B][D]
    float* sumRg = sumLg + BB * DD;    // [B][D]
    float* absS  = sumRg + BB * DD;    // [B][D]

    k_fused<<<BB * 16, 512, 0, stream>>>(X, emb, Wl, bl, Wr, br,
                                         sumLg, sumRg, absS);
    k_final<<<BB, 256, 0, stream>>>(sumLg, sumRg, absS, Wrel, brel, out);
}